// Round 25
// baseline (253.691 us; speedup 1.0000x reference)
//
#include <hip/hip_runtime.h>

#define CHN 16
#define HID 128
#define NB 32
#define NH 128
#define NW 128
#define NPIX (NB*NH*NW)      // 524288
#define TPB 256
#define XW 66                // x-tile halo width
#define XH 10                // x-tile halo rows (8 computed + 2)
#define AW2 68               // alpha halo width (+2 each side)
#define AH2 12               // alpha halo rows
#define WSTR 56              // W0 image row stride: 0..47=W0, 48=b0, 49..55=0
#define W0E_N (128*WSTR)     // 7168 shorts
#define W1E_N (CHN*HID)      // 2048 shorts

typedef __attribute__((ext_vector_type(8))) short bf16x8;
typedef __attribute__((ext_vector_type(4))) float f32x4;
typedef __attribute__((ext_vector_type(4))) int i32x4;

// JAX threefry2x32 (20 rounds). Verified vs Random123 test vectors.
__host__ __device__ inline void threefry2x32(unsigned k0, unsigned k1,
                                             unsigned x0, unsigned x1,
                                             unsigned &o0, unsigned &o1) {
  unsigned ks2 = 0x1BD11BDAu ^ k0 ^ k1;
  unsigned v0 = x0 + k0, v1 = x1 + k1;
#define TF_R(r) { v0 += v1; v1 = (v1 << (r)) | (v1 >> (32-(r))); v1 ^= v0; }
  TF_R(13) TF_R(15) TF_R(26) TF_R(6)
  v0 += k1;  v1 += ks2 + 1u;
  TF_R(17) TF_R(29) TF_R(16) TF_R(24)
  v0 += ks2; v1 += k0 + 2u;
  TF_R(13) TF_R(15) TF_R(26) TF_R(6)
  v0 += k0;  v1 += k1 + 3u;
  TF_R(17) TF_R(29) TF_R(16) TF_R(24)
  v0 += k1;  v1 += ks2 + 4u;
  TF_R(13) TF_R(15) TF_R(26) TF_R(6)
  v0 += ks2; v1 += k0 + 5u;
#undef TF_R
  o0 = v0; o1 = v1;
}

__device__ inline unsigned short f2bf(float f) {
  return __builtin_bit_cast(unsigned short, (__bf16)f);
}
__device__ inline unsigned pk2(float lo, float hi) {
  return (unsigned)f2bf(lo) | ((unsigned)f2bf(hi) << 16);
}
__device__ inline float bflo(int u) {
  return __builtin_bit_cast(float, (unsigned)u << 16);
}
__device__ inline float bfhi(int u) {
  return __builtin_bit_cast(float, (unsigned)u & 0xFFFF0000u);
}

// One-shot: pre-convert weights to bf16 images (bit-identical RNE to staged cvt).
__global__ __launch_bounds__(TPB) void prep_weights(
    const float* __restrict__ W0g, const float* __restrict__ b0g,
    const float* __restrict__ W1g,
    short* __restrict__ W0e, short* __restrict__ W1e)
{
  const int idx = blockIdx.x * TPB + threadIdx.x;
  if (idx < W0E_N) {
    const int o = idx / WSTR, k = idx - o * WSTR;
    float v = 0.f;
    if (k < 48) v = W0g[o * 48 + k];
    else if (k == 48) v = b0g[o];
    W0e[idx] = (short)f2bf(v);
  } else if (idx < W0E_N + W1E_N) {
    const int j = idx - W0E_N;
    W1e[j] = (short)f2bf(W1g[j]);
  }
}

// ---- shared core (r24-verified numerics; 8-row tile, INTERLEAVED halves) ----
// Both halves' preambles computed up front; one kt_o loop feeds both halves'
// MFMA chains per W0-fragment read (2x MFMA density, 2 independent chains).
template <int STAGE_MASK>
__device__ __forceinline__ void ca_core(
    const float* __restrict__ xprev,
    const unsigned char* __restrict__ plIn,
    const short* __restrict__ W0e,
    const short* __restrict__ W1e,
    float* __restrict__ xmid,
    unsigned char* __restrict__ plOut,
    unsigned sk0, unsigned sk1,
    short* W0s, short* xT, float* aT, float* aT2, unsigned char* lifeB)
{
  const int tid = threadIdx.x;
  const int w = tid >> 6, l = tid & 63;
  const int lc = l & 15, lg = l >> 4;

  const int bb = blockIdx.x >> 5;           // batch
  const int t5 = blockIdx.x & 31;
  const int R0 = (t5 >> 1) << 3;            // tile row base (8 rows)
  const int C0 = (t5 & 1) << 6;             // tile col base (64 cols)

  // ---- stage W0 image (pure bf16x8 memcpy from ws) ----
  for (int i = tid * 8; i < W0E_N; i += TPB * 8)
    *(bf16x8*)&W0s[i] = *(const bf16x8*)&W0e[i];

  if (STAGE_MASK) {
    for (int h2 = tid; h2 < AH2 * AW2; h2 += TPB) {
      const int r2 = h2 / AW2, c2 = h2 - r2 * AW2;
      const int Rg = R0 + r2 - 2, Cg = C0 + c2 - 2;
      aT2[h2] = ((unsigned)Rg < NH && (unsigned)Cg < NW)
          ? xprev[(((size_t)bb * NH + Rg) * NW + Cg) * CHN + 3] : -1e30f;
    }
    __syncthreads();
  }

  // ---- stage x halo tile (bf16, masked if STAGE_MASK) + alpha tile (f32) ----
  for (int h = tid; h < XH * XW; h += TPB) {
    const int r = h / XW, c = h - r * XW;
    const int R = R0 + r - 1, C = C0 + c - 1;
    float4 v0, v1, v2, v3;
    float av;
    unsigned char lf = 0;
    if ((unsigned)R < NH && (unsigned)C < NW) {
      const size_t P = ((size_t)bb * NH + R) * NW + C;
      const float* s = xprev + P * CHN;
      v0 = *(const float4*)(s);
      v1 = *(const float4*)(s + 4);
      v2 = *(const float4*)(s + 8);
      v3 = *(const float4*)(s + 12);
      if (STAGE_MASK) {
        float pool = -1e30f;
#pragma unroll
        for (int dr = 0; dr < 3; ++dr)
#pragma unroll
          for (int dc = 0; dc < 3; ++dc)
            pool = fmaxf(pool, aT2[(r + dr) * AW2 + (c + dc)]);
        lf = ((plIn[P] != 0) && (pool > 0.1f)) ? (unsigned char)1 : (unsigned char)0;
        const float m = (float)lf;
        v0.x *= m; v0.y *= m; v0.z *= m; v0.w *= m;
        v1.x *= m; v1.y *= m; v1.z *= m; v1.w *= m;
        v2.x *= m; v2.y *= m; v2.z *= m; v2.w *= m;
        v3.x *= m; v3.y *= m; v3.z *= m; v3.w *= m;
      } else {
        lf = 1;
      }
      av = v0.w;
    } else {
      v0 = v1 = v2 = v3 = (float4){0.f, 0.f, 0.f, 0.f};
      av = -1e30f;
    }
    i32x4 u;
    u[0] = (int)pk2(v0.x, v0.y); u[1] = (int)pk2(v0.z, v0.w);
    u[2] = (int)pk2(v1.x, v1.y); u[3] = (int)pk2(v1.z, v1.w);
    *(i32x4*)&xT[h * CHN] = u;
    u[0] = (int)pk2(v2.x, v2.y); u[1] = (int)pk2(v2.z, v2.w);
    u[2] = (int)pk2(v3.x, v3.y); u[3] = (int)pk2(v3.z, v3.w);
    *(i32x4*)&xT[h * CHN + 8] = u;
    aT[h] = av;
    lifeB[h] = lf;
  }

  // ---- W1 A-fragments: direct bf16 loads from ws image ----
  bf16x8 W1f[4];
#pragma unroll
  for (int kt = 0; kt < 4; ++kt)
    W1f[kt] = *(const bf16x8*)&W1e[lc * HID + kt * 32 + (lg << 3)];

  __syncthreads();   // xT/aT/lifeB/W0s visible

  const bf16x8 zero8 = {};
  bf16x8 one8 = {};
  one8[0] = (short)0x3F80;
  const int choff = (lg & 1) << 3;
  const bool gH = (lg >= 2);
  const int sA = gH ? XW * CHN : CHN;
  const int sB = gH ? CHN : XW * CHN;

  // ============ BOTH halves' preambles up front (2 independent chains) ============
  unsigned long long fmaskA[2];
  bf16x8 Yf[2][4][2];
  float4 xpre[2][4];
  f32x4 dxacc[2][4];

#pragma unroll
  for (int hf = 0; hf < 2; ++hf) {
    const int rw = (hf << 2) + w;
    const int p = (bb * NH + R0 + rw) * NW + C0 + l;

    {
      unsigned b1_, b2_;
      threefry2x32(sk0, sk1, 0u, (unsigned)p, b1_, b2_);
      fmaskA[hf] = __ballot(((b1_ ^ b2_) & 0x80000000u) == 0u);
    }
    {
      float am = -1e30f;
#pragma unroll
      for (int dr = 0; dr < 3; ++dr)
#pragma unroll
        for (int dc = 0; dc < 3; ++dc)
          am = fmaxf(am, aT[(rw + dr) * XW + (l + dc)]);
      plOut[p] = (am > 0.1f) ? (unsigned char)1 : (unsigned char)0;
    }

#pragma unroll
    for (int m = 0; m < 4; ++m) {
      const int q = (m << 4) + lc;
      const int base = ((rw + 1) * XW + (q + 1)) * CHN + choff;
      const bf16x8 raw = *(const bf16x8*)&xT[base];
      const i32x4 M0 = *(const i32x4*)&xT[base - sA - sB];
      const i32x4 M1 = *(const i32x4*)&xT[base - sA];
      const i32x4 M2 = *(const i32x4*)&xT[base - sA + sB];
      const i32x4 P0 = *(const i32x4*)&xT[base + sA - sB];
      const i32x4 P1 = *(const i32x4*)&xT[base + sA];
      const i32x4 P2 = *(const i32x4*)&xT[base + sA + sB];
      i32x4 res;
#pragma unroll
      for (int k = 0; k < 4; ++k) {
        const float pl_ = fmaf(2.f, bflo(P1[k]), bflo(P0[k])) + bflo(P2[k]);
        const float ml_ = fmaf(2.f, bflo(M1[k]), bflo(M0[k])) + bflo(M2[k]);
        const float ph_ = fmaf(2.f, bfhi(P1[k]), bfhi(P0[k])) + bfhi(P2[k]);
        const float mh_ = fmaf(2.f, bfhi(M1[k]), bfhi(M0[k])) + bfhi(M2[k]);
        res[k] = (int)pk2((pl_ - ml_) * 0.125f, (ph_ - mh_) * 0.125f);
      }
      const bf16x8 st = __builtin_bit_cast(bf16x8, res);
      Yf[hf][m][0] = gH ? st : raw;
      Yf[hf][m][1] = gH ? ((lg == 2) ? one8 : zero8) : st;
    }

#pragma unroll
    for (int m = 0; m < 4; ++m) {
      const int q = (m << 4) + lc;
      const size_t P = ((size_t)bb * NH + R0 + rw) * NW + C0 + q;
      float4 xc = *(const float4*)&xprev[P * CHN + (lg << 2)];
      const float ml = (float)lifeB[(rw + 1) * XW + (q + 1)];
      xc.x *= ml; xc.y *= ml; xc.z *= ml; xc.w *= ml;
      xpre[hf][m] = xc;
      dxacc[hf][m] = (f32x4){0.f, 0.f, 0.f, 0.f};
    }
  }

  // ============ one kt_o loop, each Wf read feeds BOTH halves ============
#pragma unroll
  for (int kt_o = 0; kt_o < 4; ++kt_o) {
    bf16x8 Wf0[2], Wf1[2];
#pragma unroll
    for (int th = 0; th < 2; ++th) {
      const int row = ((((kt_o << 1) + th) << 4) + lc) * WSTR;
      Wf0[th] = *(const bf16x8*)&W0s[row + (lg << 3)];
      Wf1[th] = (lg < 3) ? *(const bf16x8*)&W0s[row + 32 + (lg << 3)] : zero8;
    }
#pragma unroll
    for (int hf = 0; hf < 2; ++hf) {
#pragma unroll
      for (int m = 0; m < 4; ++m) {
        f32x4 a0 = __builtin_amdgcn_mfma_f32_16x16x32_bf16(
            Wf0[0], Yf[hf][m][0], (f32x4){0.f, 0.f, 0.f, 0.f}, 0, 0, 0);
        a0 = __builtin_amdgcn_mfma_f32_16x16x32_bf16(Wf1[0], Yf[hf][m][1], a0, 0, 0, 0);
        f32x4 a1 = __builtin_amdgcn_mfma_f32_16x16x32_bf16(
            Wf0[1], Yf[hf][m][0], (f32x4){0.f, 0.f, 0.f, 0.f}, 0, 0, 0);
        a1 = __builtin_amdgcn_mfma_f32_16x16x32_bf16(Wf1[1], Yf[hf][m][1], a1, 0, 0, 0);
        unsigned xa = pk2(fmaxf(a0[0], 0.f), fmaxf(a0[1], 0.f));
        unsigned xb = pk2(fmaxf(a0[2], 0.f), fmaxf(a0[3], 0.f));
        unsigned ya = pk2(fmaxf(a1[0], 0.f), fmaxf(a1[1], 0.f));
        unsigned yb = pk2(fmaxf(a1[2], 0.f), fmaxf(a1[3], 0.f));
        asm("v_permlane32_swap_b32 %0, %1" : "+v"(xa), "+v"(ya));
        asm("v_permlane32_swap_b32 %0, %1" : "+v"(xb), "+v"(yb));
        asm("v_permlane16_swap_b32 %0, %1" : "+v"(xa), "+v"(ya));
        asm("v_permlane16_swap_b32 %0, %1" : "+v"(xb), "+v"(yb));
        i32x4 bfr;
        bfr[0] = (int)xa; bfr[1] = (int)xb; bfr[2] = (int)ya; bfr[3] = (int)yb;
        dxacc[hf][m] = __builtin_amdgcn_mfma_f32_16x16x32_bf16(
            W1f[kt_o], __builtin_bit_cast(bf16x8, bfr), dxacc[hf][m], 0, 0, 0);
      }
    }
  }

  // ============ epilogues, both halves ============
#pragma unroll
  for (int hf = 0; hf < 2; ++hf) {
    const int rw = (hf << 2) + w;
#pragma unroll
    for (int m = 0; m < 4; ++m) {
      const int q = (m << 4) + lc;
      const size_t P = ((size_t)bb * NH + R0 + rw) * NW + C0 + q;
      const float f = (float)((fmaskA[hf] >> q) & 1ull);
      float4 xm;
      xm.x = fmaf(dxacc[hf][m][0], f, xpre[hf][m].x);
      xm.y = fmaf(dxacc[hf][m][1], f, xpre[hf][m].y);
      xm.z = fmaf(dxacc[hf][m][2], f, xpre[hf][m].z);
      xm.w = fmaf(dxacc[hf][m][3], f, xpre[hf][m].w);
      *(float4*)&xmid[P * CHN + (lg << 2)] = xm;
    }
  }
}

__global__ __launch_bounds__(TPB, 2) void ca_step_a(
    const float* __restrict__ xin,
    const short* __restrict__ W0e, const short* __restrict__ W1e,
    float* __restrict__ xmid, unsigned char* __restrict__ plOut,
    unsigned sk0, unsigned sk1)
{
  __shared__ __align__(16) short W0s[W0E_N];
  __shared__ __align__(16) short xT[XH * XW * CHN];
  __shared__ float aT[XH * XW];
  __shared__ unsigned char lifeB[XH * XW];
  ca_core<0>(xin, nullptr, W0e, W1e, xmid, plOut, sk0, sk1,
             W0s, xT, aT, nullptr, lifeB);
}

__global__ __launch_bounds__(TPB, 2) void ca_step_f(
    const float* __restrict__ xprev,
    const unsigned char* __restrict__ plIn,
    const short* __restrict__ W0e, const short* __restrict__ W1e,
    float* __restrict__ xmid, unsigned char* __restrict__ plOut,
    unsigned sk0, unsigned sk1)
{
  __shared__ __align__(16) short W0s[W0E_N];
  __shared__ __align__(16) short xT[XH * XW * CHN];
  __shared__ float aT[XH * XW];
  __shared__ float aT2[AH2 * AW2];
  __shared__ unsigned char lifeB[XH * XW];
  ca_core<1>(xprev, plIn, W0e, W1e, xmid, plOut, sk0, sk1,
             W0s, xT, aT, aT2, lifeB);
}

// Final masking: x_out = xmid * (plIn & pool3x3(xmid alpha) > 0.1)
__global__ __launch_bounds__(TPB) void ca_step_b(
    const float* __restrict__ xmid,
    const unsigned char* __restrict__ plIn,
    float* __restrict__ xout)
{
  const int p = blockIdx.x * TPB + threadIdx.x;
  const int j = p & (NW - 1);
  const int i = (p >> 7) & (NH - 1);
  float pmax = -1e30f;
#pragma unroll
  for (int dh = 0; dh < 3; ++dh) {
#pragma unroll
    for (int dw = 0; dw < 3; ++dw) {
      const int ii = i + dh - 1, jj = j + dw - 1;
      if ((unsigned)ii < NH && (unsigned)jj < NW)
        pmax = fmaxf(pmax, xmid[((size_t)p + (dh - 1) * NW + (dw - 1)) * CHN + 3]);
    }
  }
  const float m = ((pmax > 0.1f) && (plIn[p] != 0)) ? 1.f : 0.f;
  const float* src = xmid + (size_t)p * CHN;
  float4 a = *(const float4*)(src);
  float4 b = *(const float4*)(src + 4);
  float4 c = *(const float4*)(src + 8);
  float4 d = *(const float4*)(src + 12);
  a.x *= m; a.y *= m; a.z *= m; a.w *= m;
  b.x *= m; b.y *= m; b.z *= m; b.w *= m;
  c.x *= m; c.y *= m; c.z *= m; c.w *= m;
  d.x *= m; d.y *= m; d.z *= m; d.w *= m;
  float* dst = xout + (size_t)p * CHN;
  *(float4*)(dst)      = a;
  *(float4*)(dst + 4)  = b;
  *(float4*)(dst + 8)  = c;
  *(float4*)(dst + 12) = d;
}

extern "C" void kernel_launch(void* const* d_in, const int* in_sizes, int n_in,
                              void* d_out, int out_size, void* d_ws, size_t ws_size,
                              hipStream_t stream) {
  const float* x  = (const float*)d_in[0];
  const float* W0 = (const float*)d_in[1];
  const float* b0 = (const float*)d_in[2];
  const float* W1 = (const float*)d_in[3];
  float* out = (float*)d_out;

  char* ws = (char*)d_ws;
  float* X = (float*)ws;                                        // NPIX*16 f32 (33.55MB)
  unsigned char* pl0 = (unsigned char*)(ws + (size_t)NPIX * CHN * 4);
  unsigned char* pl1 = pl0 + NPIX;
  short* W0e = (short*)(pl1 + NPIX);                            // +14336 B
  short* W1e = W0e + W0E_N;                                     // +4096 B (total 34.62MB)

  const dim3 gridS(NPIX / 512), block(TPB);   // 8x64 tile = 512 px/block
  const dim3 gridB(NPIX / TPB);
  unsigned k0[4], k1[4];
  for (int s = 0; s < 4; ++s) threefry2x32(0u, 42u, 0u, (unsigned)s, k0[s], k1[s]);

  prep_weights<<<(W0E_N + W1E_N + TPB - 1) / TPB, block, 0, stream>>>(W0, b0, W1, W0e, W1e);
  // A(x)->out,pl0 ; A'(out)->X,pl1 ; A'(X)->out,pl0 ; A'(out)->X,pl1 ; B(X,pl1)->out
  ca_step_a<<<gridS, block, 0, stream>>>(x, W0e, W1e, out, pl0, k0[0], k1[0]);
  ca_step_f<<<gridS, block, 0, stream>>>(out, pl0, W0e, W1e, X, pl1, k0[1], k1[1]);
  ca_step_f<<<gridS, block, 0, stream>>>(X, pl1, W0e, W1e, out, pl0, k0[2], k1[2]);
  ca_step_f<<<gridS, block, 0, stream>>>(out, pl0, W0e, W1e, X, pl1, k0[3], k1[3]);
  ca_step_b<<<gridB, block, 0, stream>>>(X, pl1, out);
}

// Round 26
// 171.594 us; speedup vs baseline: 1.4784x; 1.4784x over previous
//
#include <hip/hip_runtime.h>

#define CHN 16
#define HID 128
#define NB 32
#define NH 128
#define NW 128
#define NPIX (NB*NH*NW)      // 524288
#define TPB 256
#define XW 66                // x-tile halo width
#define XH 10                // x-tile halo rows (8 computed + 2)
#define AW2 68               // alpha halo width (+2 each side)
#define AH2 12               // alpha halo rows
#define WSTR 56              // W0s row stride: 0..47=W0, 48=b0, 49..55=0

typedef __attribute__((ext_vector_type(8))) short bf16x8;
typedef __attribute__((ext_vector_type(4))) float f32x4;
typedef __attribute__((ext_vector_type(4))) int i32x4;

// JAX threefry2x32 (20 rounds). Verified vs Random123 test vectors.
__host__ __device__ inline void threefry2x32(unsigned k0, unsigned k1,
                                             unsigned x0, unsigned x1,
                                             unsigned &o0, unsigned &o1) {
  unsigned ks2 = 0x1BD11BDAu ^ k0 ^ k1;
  unsigned v0 = x0 + k0, v1 = x1 + k1;
#define TF_R(r) { v0 += v1; v1 = (v1 << (r)) | (v1 >> (32-(r))); v1 ^= v0; }
  TF_R(13) TF_R(15) TF_R(26) TF_R(6)
  v0 += k1;  v1 += ks2 + 1u;
  TF_R(17) TF_R(29) TF_R(16) TF_R(24)
  v0 += ks2; v1 += k0 + 2u;
  TF_R(13) TF_R(15) TF_R(26) TF_R(6)
  v0 += k0;  v1 += k1 + 3u;
  TF_R(17) TF_R(29) TF_R(16) TF_R(24)
  v0 += k1;  v1 += ks2 + 4u;
  TF_R(13) TF_R(15) TF_R(26) TF_R(6)
  v0 += ks2; v1 += k0 + 5u;
#undef TF_R
  o0 = v0; o1 = v1;
}

__device__ inline unsigned short f2bf(float f) {
  return __builtin_bit_cast(unsigned short, (__bf16)f);
}
__device__ inline unsigned pk2(float lo, float hi) {
  return (unsigned)f2bf(lo) | ((unsigned)f2bf(hi) << 16);
}
__device__ inline bf16x8 cvt8(float4 a, float4 b) {
  i32x4 r;
  r[0] = (int)pk2(a.x, a.y); r[1] = (int)pk2(a.z, a.w);
  r[2] = (int)pk2(b.x, b.y); r[3] = (int)pk2(b.z, b.w);
  return __builtin_bit_cast(bf16x8, r);
}
__device__ inline float bflo(int u) {
  return __builtin_bit_cast(float, (unsigned)u << 16);
}
__device__ inline float bfhi(int u) {
  return __builtin_bit_cast(float, (unsigned)u & 0xFFFF0000u);
}

// ---- shared core (r22-verified, best known: 171.8us): 8-row tile, 2 halves ----
// STAGE_MASK=1 fuses previous step's post-life mask into staging.
template <int STAGE_MASK>
__device__ __forceinline__ void ca_core(
    const float* __restrict__ xprev,
    const unsigned char* __restrict__ plIn,
    const float* __restrict__ W0g,
    const float* __restrict__ b0g,
    const float* __restrict__ W1g,
    float* __restrict__ xmid,
    unsigned char* __restrict__ plOut,
    unsigned sk0, unsigned sk1,
    short* W0s, short* xT, float* aT, float* aT2, unsigned char* lifeB)
{
  const int tid = threadIdx.x;
  const int w = tid >> 6, l = tid & 63;
  const int lc = l & 15, lg = l >> 4;

  const int bb = blockIdx.x >> 5;           // batch
  const int t5 = blockIdx.x & 31;
  const int R0 = (t5 >> 1) << 3;            // tile row base (8 rows)
  const int C0 = (t5 & 1) << 6;             // tile col base (64 cols)

  // ---- stage W0 (f32->bf16) + bias col 48 + zero pad ----
  {
    const int o = tid >> 1;
    if ((tid & 1) == 0) {
#pragma unroll
      for (int k = 0; k < 24; k += 2)
        *(unsigned*)&W0s[o * WSTR + k] = pk2(W0g[o * 48 + k], W0g[o * 48 + k + 1]);
    } else {
#pragma unroll
      for (int k = 24; k < 48; k += 2)
        *(unsigned*)&W0s[o * WSTR + k] = pk2(W0g[o * 48 + k], W0g[o * 48 + k + 1]);
      *(unsigned*)&W0s[o * WSTR + 48] = (unsigned)f2bf(b0g[o]);
      *(unsigned*)&W0s[o * WSTR + 50] = 0u;
      *(unsigned*)&W0s[o * WSTR + 52] = 0u;
      *(unsigned*)&W0s[o * WSTR + 54] = 0u;
    }
  }

  if (STAGE_MASK) {
    // stage raw xprev alpha (+2 halo) for the fused post-life pool
    for (int h2 = tid; h2 < AH2 * AW2; h2 += TPB) {
      const int r2 = h2 / AW2, c2 = h2 - r2 * AW2;
      const int Rg = R0 + r2 - 2, Cg = C0 + c2 - 2;
      aT2[h2] = ((unsigned)Rg < NH && (unsigned)Cg < NW)
          ? xprev[(((size_t)bb * NH + Rg) * NW + Cg) * CHN + 3] : -1e30f;
    }
    __syncthreads();
  }

  // ---- stage x halo tile (bf16, masked if STAGE_MASK) + alpha tile (f32) ----
  for (int h = tid; h < XH * XW; h += TPB) {
    const int r = h / XW, c = h - r * XW;
    const int R = R0 + r - 1, C = C0 + c - 1;
    float4 v0, v1, v2, v3;
    float av;
    unsigned char lf = 0;
    if ((unsigned)R < NH && (unsigned)C < NW) {
      const size_t P = ((size_t)bb * NH + R) * NW + C;
      const float* s = xprev + P * CHN;
      v0 = *(const float4*)(s);
      v1 = *(const float4*)(s + 4);
      v2 = *(const float4*)(s + 8);
      v3 = *(const float4*)(s + 12);
      if (STAGE_MASK) {
        float pool = -1e30f;
#pragma unroll
        for (int dr = 0; dr < 3; ++dr)
#pragma unroll
          for (int dc = 0; dc < 3; ++dc)
            pool = fmaxf(pool, aT2[(r + dr) * AW2 + (c + dc)]);
        lf = ((plIn[P] != 0) && (pool > 0.1f)) ? (unsigned char)1 : (unsigned char)0;
        const float m = (float)lf;
        v0.x *= m; v0.y *= m; v0.z *= m; v0.w *= m;
        v1.x *= m; v1.y *= m; v1.z *= m; v1.w *= m;
        v2.x *= m; v2.y *= m; v2.z *= m; v2.w *= m;
        v3.x *= m; v3.y *= m; v3.z *= m; v3.w *= m;
      } else {
        lf = 1;
      }
      av = v0.w;
    } else {
      v0 = v1 = v2 = v3 = (float4){0.f, 0.f, 0.f, 0.f};
      av = -1e30f;
    }
    i32x4 u;
    u[0] = (int)pk2(v0.x, v0.y); u[1] = (int)pk2(v0.z, v0.w);
    u[2] = (int)pk2(v1.x, v1.y); u[3] = (int)pk2(v1.z, v1.w);
    *(i32x4*)&xT[h * CHN] = u;
    u[0] = (int)pk2(v2.x, v2.y); u[1] = (int)pk2(v2.z, v2.w);
    u[2] = (int)pk2(v3.x, v3.y); u[3] = (int)pk2(v3.z, v3.w);
    *(i32x4*)&xT[h * CHN + 8] = u;
    aT[h] = av;
    lifeB[h] = lf;
  }

  // ---- W1 A-fragments (once per block) ----
  bf16x8 W1f[4];
#pragma unroll
  for (int kt = 0; kt < 4; ++kt) {
    const float* src = &W1g[lc * HID + kt * 32 + (lg << 3)];
    W1f[kt] = cvt8(*(const float4*)(src), *(const float4*)(src + 4));
  }

  __syncthreads();   // xT/aT/lifeB/W0s visible

  const bf16x8 zero8 = {};
  bf16x8 one8 = {};
  one8[0] = (short)0x3F80;
  const int choff = (lg & 1) << 3;
  const bool gH = (lg >= 2);
  const int sA = gH ? XW * CHN : CHN;
  const int sB = gH ? CHN : XW * CHN;

  // ================= two sequential 4-row halves =================
#pragma unroll
  for (int hf = 0; hf < 2; ++hf) {
    const int rw = (hf << 2) + w;                    // tile row (0..7) this wave
    const int p = (bb * NH + R0 + rw) * NW + C0 + l; // own pixel for fire/plOut

    unsigned long long fmask;
    {
      unsigned b1_, b2_;
      threefry2x32(sk0, sk1, 0u, (unsigned)p, b1_, b2_);
      fmask = __ballot(((b1_ ^ b2_) & 0x80000000u) == 0u);
    }

    // pre_life of staged (masked) x -> plOut
    {
      float am = -1e30f;
#pragma unroll
      for (int dr = 0; dr < 3; ++dr)
#pragma unroll
        for (int dc = 0; dc < 3; ++dc)
          am = fmaxf(am, aT[(rw + dr) * XW + (l + dc)]);
      plOut[p] = (am > 0.1f) ? (unsigned char)1 : (unsigned char)0;
    }

    // Yf fragments from xT (r19/r22-verified stencil)
    bf16x8 Yf[4][2];
#pragma unroll
    for (int m = 0; m < 4; ++m) {
      const int q = (m << 4) + lc;
      const int base = ((rw + 1) * XW + (q + 1)) * CHN + choff;
      const bf16x8 raw = *(const bf16x8*)&xT[base];
      const i32x4 M0 = *(const i32x4*)&xT[base - sA - sB];
      const i32x4 M1 = *(const i32x4*)&xT[base - sA];
      const i32x4 M2 = *(const i32x4*)&xT[base - sA + sB];
      const i32x4 P0 = *(const i32x4*)&xT[base + sA - sB];
      const i32x4 P1 = *(const i32x4*)&xT[base + sA];
      const i32x4 P2 = *(const i32x4*)&xT[base + sA + sB];
      i32x4 res;
#pragma unroll
      for (int k = 0; k < 4; ++k) {
        const float pl_ = fmaf(2.f, bflo(P1[k]), bflo(P0[k])) + bflo(P2[k]);
        const float ml_ = fmaf(2.f, bflo(M1[k]), bflo(M0[k])) + bflo(M2[k]);
        const float ph_ = fmaf(2.f, bfhi(P1[k]), bfhi(P0[k])) + bfhi(P2[k]);
        const float mh_ = fmaf(2.f, bfhi(M1[k]), bfhi(M0[k])) + bfhi(M2[k]);
        res[k] = (int)pk2((pl_ - ml_) * 0.125f, (ph_ - mh_) * 0.125f);
      }
      const bf16x8 st = __builtin_bit_cast(bf16x8, res);
      Yf[m][0] = gH ? st : raw;
      Yf[m][1] = gH ? ((lg == 2) ? one8 : zero8) : st;
    }

    // T14 prefetch: masked exact-f32 residual
    float4 xpre[4];
#pragma unroll
    for (int m = 0; m < 4; ++m) {
      const int q = (m << 4) + lc;
      const size_t P = ((size_t)bb * NH + R0 + rw) * NW + C0 + q;
      float4 xc = *(const float4*)&xprev[P * CHN + (lg << 2)];
      const float ml = (float)lifeB[(rw + 1) * XW + (q + 1)];
      xc.x *= ml; xc.y *= ml; xc.z *= ml; xc.w *= ml;
      xpre[m] = xc;
    }

    f32x4 dxacc[4];
#pragma unroll
    for (int m = 0; m < 4; ++m) dxacc[m] = (f32x4){0.f, 0.f, 0.f, 0.f};

#pragma unroll
    for (int kt_o = 0; kt_o < 4; ++kt_o) {
      bf16x8 Wf0[2], Wf1[2];
#pragma unroll
      for (int th = 0; th < 2; ++th) {
        const int row = ((((kt_o << 1) + th) << 4) + lc) * WSTR;
        Wf0[th] = *(const bf16x8*)&W0s[row + (lg << 3)];
        Wf1[th] = (lg < 3) ? *(const bf16x8*)&W0s[row + 32 + (lg << 3)] : zero8;
      }
#pragma unroll
      for (int m = 0; m < 4; ++m) {
        f32x4 a0 = __builtin_amdgcn_mfma_f32_16x16x32_bf16(
            Wf0[0], Yf[m][0], (f32x4){0.f, 0.f, 0.f, 0.f}, 0, 0, 0);
        a0 = __builtin_amdgcn_mfma_f32_16x16x32_bf16(Wf1[0], Yf[m][1], a0, 0, 0, 0);
        f32x4 a1 = __builtin_amdgcn_mfma_f32_16x16x32_bf16(
            Wf0[1], Yf[m][0], (f32x4){0.f, 0.f, 0.f, 0.f}, 0, 0, 0);
        a1 = __builtin_amdgcn_mfma_f32_16x16x32_bf16(Wf1[1], Yf[m][1], a1, 0, 0, 0);
        unsigned xa = pk2(fmaxf(a0[0], 0.f), fmaxf(a0[1], 0.f));
        unsigned xb = pk2(fmaxf(a0[2], 0.f), fmaxf(a0[3], 0.f));
        unsigned ya = pk2(fmaxf(a1[0], 0.f), fmaxf(a1[1], 0.f));
        unsigned yb = pk2(fmaxf(a1[2], 0.f), fmaxf(a1[3], 0.f));
        asm("v_permlane32_swap_b32 %0, %1" : "+v"(xa), "+v"(ya));
        asm("v_permlane32_swap_b32 %0, %1" : "+v"(xb), "+v"(yb));
        asm("v_permlane16_swap_b32 %0, %1" : "+v"(xa), "+v"(ya));
        asm("v_permlane16_swap_b32 %0, %1" : "+v"(xb), "+v"(yb));
        i32x4 bfr;
        bfr[0] = (int)xa; bfr[1] = (int)xb; bfr[2] = (int)ya; bfr[3] = (int)yb;
        dxacc[m] = __builtin_amdgcn_mfma_f32_16x16x32_bf16(
            W1f[kt_o], __builtin_bit_cast(bf16x8, bfr), dxacc[m], 0, 0, 0);
      }
    }

    // epilogue: xmid = staged_x + dx*fire
#pragma unroll
    for (int m = 0; m < 4; ++m) {
      const int q = (m << 4) + lc;
      const size_t P = ((size_t)bb * NH + R0 + rw) * NW + C0 + q;
      const float f = (float)((fmask >> q) & 1ull);
      float4 xm;
      xm.x = fmaf(dxacc[m][0], f, xpre[m].x);
      xm.y = fmaf(dxacc[m][1], f, xpre[m].y);
      xm.z = fmaf(dxacc[m][2], f, xpre[m].z);
      xm.w = fmaf(dxacc[m][3], f, xpre[m].w);
      *(float4*)&xmid[P * CHN + (lg << 2)] = xm;
    }
  }
}

__global__ __launch_bounds__(TPB, 2) void ca_step_a(
    const float* __restrict__ xin,
    const float* __restrict__ W0g, const float* __restrict__ b0g,
    const float* __restrict__ W1g,
    float* __restrict__ xmid, unsigned char* __restrict__ plOut,
    unsigned sk0, unsigned sk1)
{
  __shared__ __align__(16) short W0s[128 * WSTR];
  __shared__ __align__(16) short xT[XH * XW * CHN];
  __shared__ float aT[XH * XW];
  __shared__ unsigned char lifeB[XH * XW];
  ca_core<0>(xin, nullptr, W0g, b0g, W1g, xmid, plOut, sk0, sk1,
             W0s, xT, aT, nullptr, lifeB);
}

__global__ __launch_bounds__(TPB, 2) void ca_step_f(
    const float* __restrict__ xprev,
    const unsigned char* __restrict__ plIn,
    const float* __restrict__ W0g, const float* __restrict__ b0g,
    const float* __restrict__ W1g,
    float* __restrict__ xmid, unsigned char* __restrict__ plOut,
    unsigned sk0, unsigned sk1)
{
  __shared__ __align__(16) short W0s[128 * WSTR];
  __shared__ __align__(16) short xT[XH * XW * CHN];
  __shared__ float aT[XH * XW];
  __shared__ float aT2[AH2 * AW2];
  __shared__ unsigned char lifeB[XH * XW];
  ca_core<1>(xprev, plIn, W0g, b0g, W1g, xmid, plOut, sk0, sk1,
             W0s, xT, aT, aT2, lifeB);
}

// Final masking: x_out = xmid * (plIn & pool3x3(xmid alpha) > 0.1)
__global__ __launch_bounds__(TPB) void ca_step_b(
    const float* __restrict__ xmid,
    const unsigned char* __restrict__ plIn,
    float* __restrict__ xout)
{
  const int p = blockIdx.x * TPB + threadIdx.x;
  const int j = p & (NW - 1);
  const int i = (p >> 7) & (NH - 1);
  float pmax = -1e30f;
#pragma unroll
  for (int dh = 0; dh < 3; ++dh) {
#pragma unroll
    for (int dw = 0; dw < 3; ++dw) {
      const int ii = i + dh - 1, jj = j + dw - 1;
      if ((unsigned)ii < NH && (unsigned)jj < NW)
        pmax = fmaxf(pmax, xmid[((size_t)p + (dh - 1) * NW + (dw - 1)) * CHN + 3]);
    }
  }
  const float m = ((pmax > 0.1f) && (plIn[p] != 0)) ? 1.f : 0.f;
  const float* src = xmid + (size_t)p * CHN;
  float4 a = *(const float4*)(src);
  float4 b = *(const float4*)(src + 4);
  float4 c = *(const float4*)(src + 8);
  float4 d = *(const float4*)(src + 12);
  a.x *= m; a.y *= m; a.z *= m; a.w *= m;
  b.x *= m; b.y *= m; b.z *= m; b.w *= m;
  c.x *= m; c.y *= m; c.z *= m; c.w *= m;
  d.x *= m; d.y *= m; d.z *= m; d.w *= m;
  float* dst = xout + (size_t)p * CHN;
  *(float4*)(dst)      = a;
  *(float4*)(dst + 4)  = b;
  *(float4*)(dst + 8)  = c;
  *(float4*)(dst + 12) = d;
}

extern "C" void kernel_launch(void* const* d_in, const int* in_sizes, int n_in,
                              void* d_out, int out_size, void* d_ws, size_t ws_size,
                              hipStream_t stream) {
  const float* x  = (const float*)d_in[0];
  const float* W0 = (const float*)d_in[1];
  const float* b0 = (const float*)d_in[2];
  const float* W1 = (const float*)d_in[3];
  float* out = (float*)d_out;

  char* ws = (char*)d_ws;
  float* X = (float*)ws;                                        // NPIX*16 f32
  unsigned char* pl0 = (unsigned char*)(ws + (size_t)NPIX * CHN * 4);
  unsigned char* pl1 = pl0 + NPIX;

  const dim3 gridS(NPIX / 512), block(TPB);   // 8x64 tile = 512 px/block
  const dim3 gridB(NPIX / TPB);
  unsigned k0[4], k1[4];
  for (int s = 0; s < 4; ++s) threefry2x32(0u, 42u, 0u, (unsigned)s, k0[s], k1[s]);

  // A(x)->out,pl0 ; A'(out)->X,pl1 ; A'(X)->out,pl0 ; A'(out)->X,pl1 ; B(X,pl1)->out
  ca_step_a<<<gridS, block, 0, stream>>>(x, W0, b0, W1, out, pl0, k0[0], k1[0]);
  ca_step_f<<<gridS, block, 0, stream>>>(out, pl0, W0, b0, W1, X, pl1, k0[1], k1[1]);
  ca_step_f<<<gridS, block, 0, stream>>>(X, pl1, W0, b0, W1, out, pl0, k0[2], k1[2]);
  ca_step_f<<<gridS, block, 0, stream>>>(out, pl0, W0, b0, W1, X, pl1, k0[3], k1[3]);
  ca_step_b<<<gridB, block, 0, stream>>>(X, pl1, out);
}